// Round 17
// baseline (219.164 us; speedup 1.0000x reference)
//
#include <hip/hip_runtime.h>
#include <math.h>

#define HID 768
#define NB  64
#define HV  384

__device__ __forceinline__ float4 ld4(const float* p) { return *(const float4*)p; }

// ---------------------------------------------------------------------------
// K1: dec1 partial (R14 measured body). Grid 384 = 24 n-tiles x 16 k-chunks.
// Also zero-inits the ticket counters (stream-ordered before dec2/gemmB,
// defeats workspace poisoning).
// ---------------------------------------------------------------------------
__global__ __launch_bounds__(256)
void dec1p_kernel(const float* __restrict__ Ws0, const float* __restrict__ bs0,
                  const float* __restrict__ Ws1, float* __restrict__ H1p,
                  int* __restrict__ cnt) {
    __shared__ float W0s[7 * 48];
    __shared__ float As[48 * 68];
    __shared__ float Bs[48 * 36];
    const int tid = threadIdx.x;
    if (blockIdx.x == 0 && tid == 0) { cnt[0] = 0; cnt[1] = 0; }
    const int n0 = (blockIdx.x % 24) * 32;
    const int kz = blockIdx.x / 24;
    const int ks = kz * 48;

    for (int e = tid; e < 7 * 48; e += 256) {
        const int r = e / 48, c = e % 48;
        W0s[e] = (r < 6) ? Ws0[(size_t)r * HID + ks + c] : bs0[ks + c];
    }
    for (int e = tid; e < 48 * 8; e += 256) {
        const int k = e >> 3, nq = (e & 7) * 4;
        *(float4*)&Bs[k * 36 + nq] = ld4(Ws1 + (size_t)(ks + k) * HID + n0 + nq);
    }
    __syncthreads();
    for (int e = tid; e < 48 * 64; e += 256) {
        const int k = e >> 6, t = e & 63;
        float v = W0s[6 * 48 + k];
        #pragma unroll
        for (int b = 0; b < 6; ++b)
            v = fmaf((float)((t >> b) & 1), W0s[b * 48 + k], v);
        As[k * 68 + t] = fmaxf(v, 0.f);
    }
    __syncthreads();

    const int tx = tid & 7, ty = tid >> 3;
    float acc[2][4] = {};
    #pragma unroll 8
    for (int kk = 0; kk < 48; ++kk) {
        const float2 a2 = *(const float2*)&As[kk * 68 + ty * 2];
        const float4 b4 = *(const float4*)&Bs[kk * 36 + tx * 4];
        const float av[2] = {a2.x, a2.y};
        const float bv[4] = {b4.x, b4.y, b4.z, b4.w};
        #pragma unroll
        for (int a = 0; a < 2; ++a)
            #pragma unroll
            for (int b = 0; b < 4; ++b)
                acc[a][b] = fmaf(av[a], bv[b], acc[a][b]);
    }
    #pragma unroll
    for (int a = 0; a < 2; ++a) {
        float4 o = make_float4(acc[a][0], acc[a][1], acc[a][2], acc[a][3]);
        *(float4*)&H1p[((size_t)kz * 64 + ty * 2 + a) * HID + n0 + tx * 4] = o;
    }
}

// ---------------------------------------------------------------------------
// K2: dec2 + plan epilogue. Body identical to R14 dec2. After pred[t] store,
// each block tickets cnt[0]; ticket 63 (all preds visible via fence+atomic
// chain) runs the identical plan ballot -> hdr. Saves the plan launch.
// ---------------------------------------------------------------------------
__global__ __launch_bounds__(256)
void dec2_kernel(const float* __restrict__ H1p, const float* __restrict__ bs1,
                 const float* __restrict__ Ws2, const float* __restrict__ bs2,
                 int* __restrict__ pred, int* __restrict__ hdr,
                 int* __restrict__ cnt) {
    __shared__ float sh[HID];
    __shared__ float plp[4][64];
    __shared__ int sh_tk;
    const int tid = threadIdx.x;
    const int t = blockIdx.x;

    for (int e = tid; e < HID / 4; e += 256) {
        const int k4 = e * 4;
        float4 v = ld4(bs1 + k4);
        #pragma unroll
        for (int z = 0; z < 16; ++z) {
            const float4 p = ld4(H1p + ((size_t)z * 64 + t) * HID + k4);
            v.x += p.x; v.y += p.y; v.z += p.z; v.w += p.w;
        }
        sh[k4 + 0] = fmaxf(v.x, 0.f);
        sh[k4 + 1] = fmaxf(v.y, 0.f);
        sh[k4 + 2] = fmaxf(v.z, 0.f);
        sh[k4 + 3] = fmaxf(v.w, 0.f);
    }
    __syncthreads();
    {
        const int n = tid & 63, part = tid >> 6;
        float p = 0.f;
        #pragma unroll 8
        for (int kk = 0; kk < 192; ++kk) {
            const int k = part * 192 + kk;
            p = fmaf(sh[k], Ws2[k * 64 + n], p);
        }
        plp[part][n] = p;
    }
    __syncthreads();
    if (tid == 0) {
        int best = 0;
        float bv = bs2[0] + plp[0][0] + plp[1][0] + plp[2][0] + plp[3][0];
        for (int n = 1; n < 64; ++n) {
            const float x = bs2[n] + plp[0][n] + plp[1][n] + plp[2][n] + plp[3][n];
            if (x > bv) { bv = x; best = n; }
        }
        pred[t] = best;
    }
    // ---- plan epilogue (ticketed) ----
    __threadfence();
    __syncthreads();
    if (tid == 0) sh_tk = atomicAdd(&cnt[0], 1);
    __syncthreads();
    if (sh_tk == 63) {
        __threadfence();
        __shared__ int present[64];
        if (tid < 64) present[tid] = 0;
        __syncthreads();
        if (tid < 64) present[pred[tid] & 63] = 1;
        __syncthreads();
        if (tid < 64) {
            const unsigned long long alive = __ballot(present[tid] != 0);
            const int P = __popcll(alive);
            const int rank = __popcll(alive & ((1ull << tid) - 1ull));
            if (tid == 0) hdr[0] = P;
            if (present[tid]) { hdr[1 + rank] = tid; hdr[65 + tid] = rank; }
            else hdr[65 + tid] = -1;
        }
    }
}

// ---------------------------------------------------------------------------
// K4: gemmA (R8/R14 measured body). 64x64 tile, 4x4 frag, BK=64,
// grid (12, 64, 6).
// ---------------------------------------------------------------------------
__global__ __launch_bounds__(256)
void gemmA_kernel(const float* __restrict__ Wi0, const float* __restrict__ bi0,
                  const float* __restrict__ Wi1, const int* __restrict__ hdr,
                  float* __restrict__ H2p) {
    __shared__ float As[64 * 68];
    __shared__ float Bs[64 * 68];
    const int tid = threadIdx.x;
    const int P = hdr[0];
    const int li = blockIdx.y;
    if (li >= P) return;
    const int s = hdr[1 + li];
    const int n0 = blockIdx.x * 64;
    const int z = blockIdx.z;
    const int tx = tid & 15, ty = tid >> 4;
    const float* arow = Wi0 + (size_t)(64 + s) * HID;
    float acc[4][4] = {};

    for (int kt = 0; kt < 2; ++kt) {
        const int k0 = z * 128 + kt * 64;
        #pragma unroll
        for (int pass = 0; pass < 4; ++pass) {
            const int c = pass * 256 + tid;
            const int m = c >> 4, kq = (c & 15) * 4;
            const float4 a1 = ld4(arow + k0 + kq);
            const float4 a2 = ld4(Wi0 + (size_t)m * HID + k0 + kq);
            const float4 bb = ld4(bi0 + k0 + kq);
            As[(kq + 0) * 68 + m] = fmaxf(a1.x + a2.x + bb.x, 0.f);
            As[(kq + 1) * 68 + m] = fmaxf(a1.y + a2.y + bb.y, 0.f);
            As[(kq + 2) * 68 + m] = fmaxf(a1.z + a2.z + bb.z, 0.f);
            As[(kq + 3) * 68 + m] = fmaxf(a1.w + a2.w + bb.w, 0.f);
        }
        #pragma unroll
        for (int pass = 0; pass < 4; ++pass) {
            const int c = pass * 256 + tid;
            const int k = c >> 4, nq = (c & 15) * 4;
            *(float4*)&Bs[k * 68 + nq] = ld4(Wi1 + (size_t)(k0 + k) * HID + n0 + nq);
        }
        __syncthreads();
        #pragma unroll 8
        for (int kk = 0; kk < 64; ++kk) {
            const float4 a4 = *(const float4*)&As[kk * 68 + ty * 4];
            const float4 b4 = *(const float4*)&Bs[kk * 68 + tx * 4];
            const float av[4] = {a4.x, a4.y, a4.z, a4.w};
            const float bv[4] = {b4.x, b4.y, b4.z, b4.w};
            #pragma unroll
            for (int a = 0; a < 4; ++a)
                #pragma unroll
                for (int b = 0; b < 4; ++b)
                    acc[a][b] = fmaf(av[a], bv[b], acc[a][b]);
        }
        __syncthreads();
    }
    float* dst = H2p + ((size_t)(z * 64 + li) * 64) * HID + n0;
    #pragma unroll
    for (int a = 0; a < 4; ++a) {
        float4 o = make_float4(acc[a][0], acc[a][1], acc[a][2], acc[a][3]);
        *(float4*)(dst + (size_t)(ty * 4 + a) * HID + tx * 4) = o;
    }
}

// ---------------------------------------------------------------------------
// K5: gemmB + reduceA epilogue. gemmB body identical to R14. All 768 blocks
// (incl. dead-li) ticket cnt[1]; tickets 512..767 map to the 256 reduceA
// jobs, spin (device-scope atomic load) until all 768 done, then run the
// identical reduceA body with lg overlaid on Ht. Spin-safe: 768 blocks
// <= 1024 resident capacity (4 blocks/CU at 34.8KB LDS). Saves a launch.
// ---------------------------------------------------------------------------
__global__ __launch_bounds__(256)
void gemmBR_kernel(const float* __restrict__ bi1, const float* __restrict__ Wi2,
                   const int* __restrict__ hdr, const float* __restrict__ H2p,
                   float* __restrict__ PLf,
                   const float* __restrict__ bi2,
                   const float* __restrict__ Wv0, const float* __restrict__ bv0,
                   const float* __restrict__ Wv1, const float* __restrict__ bv1,
                   int* __restrict__ j_tab, float* __restrict__ sig_tab,
                   int* __restrict__ cnt) {
    __shared__ float Ht[64 * 68];
    __shared__ float W2[64 * 68];
    __shared__ int sh_tk;
    const int tid = threadIdx.x;
    const int P = hdr[0];
    const int li = blockIdx.y;
    const int bx = blockIdx.x;
    const int n0 = bx * 64;
    const size_t zstep = (size_t)64 * 64 * HID;

    if (li < P) {
        for (int e = tid; e < 1024; e += 256) {
            const int m = e >> 4, nq = (e & 15) * 4;
            const float* base = H2p + ((size_t)li * 64 + m) * HID + n0 + nq;
            float4 v = ld4(base);
            #pragma unroll
            for (int z = 1; z < 6; ++z) {
                const float4 p = ld4(base + z * zstep);
                v.x += p.x; v.y += p.y; v.z += p.z; v.w += p.w;
            }
            const float4 bb = ld4(bi1 + n0 + nq);
            Ht[(nq + 0) * 68 + m] = fmaxf(v.x + bb.x, 0.f);
            Ht[(nq + 1) * 68 + m] = fmaxf(v.y + bb.y, 0.f);
            Ht[(nq + 2) * 68 + m] = fmaxf(v.z + bb.z, 0.f);
            Ht[(nq + 3) * 68 + m] = fmaxf(v.w + bb.w, 0.f);
        }
        #pragma unroll
        for (int pass = 0; pass < 4; ++pass) {
            const int c = pass * 256 + tid;
            const int cl = c >> 4, oq = (c & 15) * 4;
            *(float4*)&W2[cl * 68 + oq] = ld4(Wi2 + (size_t)(n0 + cl) * 64 + oq);
        }
        __syncthreads();
        const int tx = tid & 15, ty = tid >> 4;
        float pl_[4][4] = {};
        #pragma unroll 16
        for (int kk = 0; kk < 64; ++kk) {
            const float4 a4 = *(const float4*)&Ht[kk * 68 + ty * 4];
            const float4 b4 = *(const float4*)&W2[kk * 68 + tx * 4];
            const float av[4] = {a4.x, a4.y, a4.z, a4.w};
            const float bv[4] = {b4.x, b4.y, b4.z, b4.w};
            #pragma unroll
            for (int a = 0; a < 4; ++a)
                #pragma unroll
                for (int b = 0; b < 4; ++b)
                    pl_[a][b] = fmaf(av[a], bv[b], pl_[a][b]);
        }
        #pragma unroll
        for (int a = 0; a < 4; ++a) {
            float4 o = make_float4(pl_[a][0], pl_[a][1], pl_[a][2], pl_[a][3]);
            *(float4*)&PLf[((size_t)(bx * 64 + li) * 64 + ty * 4 + a) * 64 + tx * 4] = o;
        }
    }

    // ---- ticket + reduceA epilogue ----
    __threadfence();
    __syncthreads();
    if (tid == 0) sh_tk = atomicAdd(&cnt[1], 1);
    __syncthreads();
    const int tk = sh_tk;
    if (tk < 512) return;
    const int r = tk - 512;            // 0..255 == old reduceA blockIdx.x
    const int s = r >> 2;
    const int li2 = hdr[65 + s];
    if (li2 < 0) return;
    if (tid == 0) {
        while (__hip_atomic_load(&cnt[1], __ATOMIC_RELAXED, __HIP_MEMORY_SCOPE_AGENT) < 768) {
            __builtin_amdgcn_s_sleep(8);
        }
    }
    __syncthreads();
    __threadfence();

    float* lg = Ht;                    // overlay (Ht no longer needed)
    const int r0 = r * 16;
    const int rr = tid >> 4, q = tid & 15;
    const int i = (r0 & 63) + rr;
    float4 v = ld4(bi2 + q * 4);
    #pragma unroll
    for (int bx2 = 0; bx2 < 12; ++bx2) {
        const float4 p = ld4(PLf + ((size_t)(bx2 * 64 + li2) * 64 + i) * 64 + q * 4);
        v.x += p.x; v.y += p.y; v.z += p.z; v.w += p.w;
    }
    *(float4*)&lg[rr * 68 + q * 4] = v;
    __syncthreads();
    if (tid < 16) {
        int best = 0; float bv = lg[tid * 68];
        for (int n = 1; n < 64; ++n) {
            const float x = lg[tid * 68 + n];
            if (x > bv) { bv = x; best = n; }
        }
        j_tab[r0 + tid] = best;
    }
    {
        const int rrow = r0 + rr;
        const int ii = rrow & 63;
        const float* w1 = Wv0 + (size_t)(64 + s) * HV;
        const float* w2 = Wv0 + (size_t)ii * HV;
        float sum = 0.f;
        #pragma unroll 4
        for (int c = q; c < HV; c += 16) {
            const float hv = fmaxf(w1[c] + w2[c] + bv0[c], 0.f);
            sum = fmaf(hv, Wv1[c], sum);
        }
        #pragma unroll
        for (int m = 8; m >= 1; m >>= 1) sum += __shfl_xor(sum, m);
        if (q == 0) sig_tab[rrow] = 1.f / (1.f + expf(-(sum + bv1[0])));
    }
}

// ---------------------------------------------------------------------------
// K7: output. out[b,i] = a_bits[b, j_tab[pred[t_b]*64+i]] * sig_tab[...]
// ---------------------------------------------------------------------------
__global__ __launch_bounds__(256)
void output_kernel(const float* __restrict__ a_bits, const int* __restrict__ shift_amount,
                   const int* __restrict__ pred, const int* __restrict__ j_tab,
                   const float* __restrict__ sig_tab, float* __restrict__ out, int B) {
    const int tid = threadIdx.x;
    const int i = tid & 63;
    const int b = blockIdx.x * 4 + (tid >> 6);
    if (b >= B) return;
    const int t = shift_amount[b] & 63;
    const int s = pred[t];
    const int idx = s * 64 + i;
    const int j = j_tab[idx];
    out[(size_t)b * 64 + i] = a_bits[(size_t)b * 64 + j] * sig_tab[idx];
}

// ---------------------------------------------------------------------------
extern "C" void kernel_launch(void* const* d_in, const int* in_sizes, int n_in,
                              void* d_out, int out_size, void* d_ws, size_t ws_size,
                              hipStream_t stream) {
    const float* a_bits       = (const float*)d_in[0];
    const int*   shift_amount = (const int*)d_in[1];
    const float* Ws0 = (const float*)d_in[2];
    const float* bs0 = (const float*)d_in[3];
    const float* Ws1 = (const float*)d_in[4];
    const float* bs1 = (const float*)d_in[5];
    const float* Ws2 = (const float*)d_in[6];
    const float* bs2 = (const float*)d_in[7];
    const float* Wi0 = (const float*)d_in[8];
    const float* bi0 = (const float*)d_in[9];
    const float* Wi1 = (const float*)d_in[10];
    const float* bi1 = (const float*)d_in[11];
    const float* Wi2 = (const float*)d_in[12];
    const float* bi2 = (const float*)d_in[13];
    const float* Wv0 = (const float*)d_in[14];
    const float* bv0 = (const float*)d_in[15];
    const float* Wv1 = (const float*)d_in[16];
    const float* bv1 = (const float*)d_in[17];
    float* out = (float*)d_out;
    const int B = in_sizes[1];

    char* ws = (char*)d_ws;
    int*   pred    = (int*)ws;                  // 64 ints
    int*   j_tab   = (int*)(ws + 1024);         // 4096 ints
    float* sig_tab = (float*)(ws + 20480);      // 4096 floats
    int*   hdr     = (int*)(ws + 40960);        // P + s_of_rank[64] + rank_of_s[64]
    int*   cnt     = (int*)(ws + 49152);        // [0]=dec2 tickets, [1]=gemmB tickets
    // Aliased region at +65536 (stream-ordered reuse):
    //   H1p (dec1p->dec2): 16*64*768*4 = 3.1 MB
    //   H2p (gemmA->gemmB): 6*64*64*768*4 = 75,497,472 B
    float* H1p = (float*)(ws + 65536);
    float* H2p = (float*)(ws + 65536);
    float* PLf = (float*)(ws + 65536 + 75497472); // 12*64*64*64*4 = 12.6 MB

    dec1p_kernel<<<384, 256, 0, stream>>>(Ws0, bs0, Ws1, H1p, cnt);
    dec2_kernel<<<64, 256, 0, stream>>>(H1p, bs1, Ws2, bs2, pred, hdr, cnt);
    gemmA_kernel<<<dim3(12, 64, 6), 256, 0, stream>>>(Wi0, bi0, Wi1, hdr, H2p);
    gemmBR_kernel<<<dim3(12, 64), 256, 0, stream>>>(bi1, Wi2, hdr, H2p, PLf,
                                                    bi2, Wv0, bv0, Wv1, bv1,
                                                    j_tab, sig_tab, cnt);
    output_kernel<<<(B + 3) / 4, 256, 0, stream>>>(a_bits, shift_amount, pred,
                                                   j_tab, sig_tab, out, B);
}